// Round 1
// baseline (116.229 us; speedup 1.0000x reference)
//
#include <hip/hip_runtime.h>
#include <math.h>

// AnnealingTopKSoftMax: per-row top-8 mask + softmax over 512-wide rows.
// One wave (64 lanes) per row; lane l owns elements [l*8, l*8+8).
// Tie-break = lowest global index (matches jax.lax.top_k), which with
// lane-contiguous ownership reduces to (lowest lane, lowest local j).

#define DEPTH 512

__global__ __launch_bounds__(256, 8)
void AnnealingTopKSoftMax_kernel(const float* __restrict__ in,
                                 float* __restrict__ out,
                                 int rows) {
    const int wave = threadIdx.x >> 6;       // 0..3 (4 waves per block)
    const int lane = threadIdx.x & 63;
    const int row  = blockIdx.x * 4 + wave;
    if (row >= rows) return;

    const float* rp = in + (size_t)row * DEPTH + lane * 8;
    float4 a = *reinterpret_cast<const float4*>(rp);
    float4 b = *reinterpret_cast<const float4*>(rp + 4);
    float x[8] = {a.x, a.y, a.z, a.w, b.x, b.y, b.z, b.w};

    unsigned rem = 0xFFu;   // not-yet-consumed elements (local)
    unsigned sel = 0u;      // selected (top-8) elements (local)

    // local best among remaining: strict '>' keeps lowest j on ties
    float bv = x[0];
    int   bj = 0;
#pragma unroll
    for (int j = 1; j < 8; ++j) {
        if (x[j] > bv) { bv = x[j]; bj = j; }
    }

    float M = 0.0f;   // row max (round 0 winner)
    float S = 0.0f;   // softmax denominator over selected

#pragma unroll
    for (int r = 0; r < 8; ++r) {
        // wave-wide max of per-lane bests
        float v = bv;
#pragma unroll
        for (int off = 32; off; off >>= 1)
            v = fmaxf(v, __shfl_xor(v, off, 64));

        // winner = lowest lane holding v  (=> lowest global index)
        unsigned long long ball = __ballot(bv == v);
        int L = __ffsll(ball) - 1;

        if (r == 0) M = v;
        S += __expf(v - M);

        if (lane == L) {
            sel |= 1u << bj;
            rem &= ~(1u << bj);
            // rescan remaining local elements
            bv = -INFINITY; bj = 0;
#pragma unroll
            for (int j = 0; j < 8; ++j) {
                if ((rem >> j) & 1u) {
                    if (x[j] > bv) { bv = x[j]; bj = j; }
                }
            }
        }
    }

    const float inv = 1.0f / S;
    float o[8];
#pragma unroll
    for (int j = 0; j < 8; ++j) {
        float ej = __expf(x[j] - M) * inv;
        o[j] = ((sel >> j) & 1u) ? ej : 0.0f;
    }

    float4* op = reinterpret_cast<float4*>(out + (size_t)row * DEPTH + lane * 8);
    op[0] = make_float4(o[0], o[1], o[2], o[3]);
    op[1] = make_float4(o[4], o[5], o[6], o[7]);
}

extern "C" void kernel_launch(void* const* d_in, const int* in_sizes, int n_in,
                              void* d_out, int out_size, void* d_ws, size_t ws_size,
                              hipStream_t stream) {
    const float* in = (const float*)d_in[0];
    float* out = (float*)d_out;
    const int rows = in_sizes[0] / DEPTH;      // 131072
    const int blocks = (rows + 3) / 4;         // 4 rows (waves) per 256-thread block
    AnnealingTopKSoftMax_kernel<<<blocks, 256, 0, stream>>>(in, out, rows);
}